// Round 8
// baseline (269.699 us; speedup 1.0000x reference)
//
#include <hip/hip_runtime.h>
#include <hip/hip_cooperative_groups.h>
#include <math.h>

namespace cg = cooperative_groups;

// B=64, S=512, H=1024
#define BB 64
#define SS 512
#define HH 1024
#define K3 3072
#define KSPLIT 16
#define KCHUNK 192          // K3 / KSPLIT -> 48 float4-rows per chunk
#define RJ 4                // j-columns per wave
#define JTILE 16            // j-columns per block (4 waves x RJ)

// Transposed packed feats: FP[r][b] (float4), r = k/4 in [0,768), b in [0,64).
//   r <  256 : first-token  (k < 1024)
//   256..511 : subj-mean    (1024 <= k < 2048)
//   512..767 : obj-mean     (2048 <= k < 3072)

// ================= Fused cooperative kernel =================================
// grid 1024 x 256 threads (4 blocks/CU co-resident; 16 KB LDS; low VGPR).
// Phase 0 (blocks 0..159): build FP  (128 mean jobs + 32 transpose blocks)
// Phase 1 (all 1024):      GEMM partials  part[kp][j][b]
// Phase 2 (blocks 0..255): reduce 16 k-parts + bias + tanh -> out
__global__ __launch_bounds__(256) void fused_kernel(
    const float* __restrict__ hs,     // (B,S,H)
    const int*   __restrict__ subj,   // (B,2)
    const int*   __restrict__ obj,    // (B,2)
    const float* __restrict__ W,      // (H,3H) row-major
    const float* __restrict__ bias,   // (H)
    float4*      __restrict__ FP,     // (768,64) float4   [ws]
    float*       __restrict__ part,   // (KSPLIT,H,B)      [ws]
    float*       __restrict__ out)    // (B,H)
{
    __shared__ float4 red[4][256];    // 16 KB, phase-0 mean reduction only

    const int bid = blockIdx.x;
    const int tid = threadIdx.x;

    // ---------------- Phase 0: feats ----------------
    if (bid < 128) {                  // mean job: b = bid>>1, feat = bid&1
        const int b    = bid >> 1;
        const int feat = bid & 1;
        const int* rng = feat ? obj : subj;
        const int s0 = rng[2 * b], s1 = rng[2 * b + 1];

        const int w    = tid >> 6;    // wave 0..3
        const int lane = tid & 63;

        const float4* base = (const float4*)(hs + (size_t)b * SS * HH);

        float4 acc[4];                // q -> float4 index q*64+lane
        #pragma unroll
        for (int q = 0; q < 4; ++q) acc[q] = make_float4(0.f, 0.f, 0.f, 0.f);

        for (int s = s0 + w; s < s1; s += 4) {       // serial depth <= 8
            const float4* row = base + (size_t)s * (HH / 4);
            #pragma unroll
            for (int q = 0; q < 4; ++q) {
                float4 v = row[q * 64 + lane];
                acc[q].x += v.x; acc[q].y += v.y; acc[q].z += v.z; acc[q].w += v.w;
            }
        }

        #pragma unroll
        for (int q = 0; q < 4; ++q)
            red[w][q * 64 + lane] = acc[q];
        __syncthreads();

        float4 s = red[0][tid];
        #pragma unroll
        for (int p = 1; p < 4; ++p) {
            float4 v = red[p][tid];
            s.x += v.x; s.y += v.y; s.z += v.z; s.w += v.w;
        }
        const float inv = 1.0f / fmaxf((float)(s1 - s0), 1.0f);
        s.x *= inv; s.y *= inv; s.z *= inv; s.w *= inv;
        FP[(size_t)((1 + feat) * 256 + tid) * BB + b] = s;   // scattered 16B
    } else if (bid < 160) {           // first-token transpose, 2 b per block
        const int b2 = (bid - 128) * 2;
        #pragma unroll
        for (int i = 0; i < 2; ++i) {
            const int b = b2 + i;
            const float4 v = ((const float4*)(hs + (size_t)b * SS * HH))[tid];
            FP[(size_t)tid * BB + b] = v;
        }
    }

    cg::this_grid().sync();

    // ---------------- Phase 1: GEMM partials (all 1024 blocks) --------------
    {
        const int kp    = bid & 15;
        const int jg    = bid >> 4;             // 0..63
        const int rbase = kp * (KCHUNK / 4);    // 48 rows per chunk

        const int w    = __builtin_amdgcn_readfirstlane(tid >> 6);  // 0..3
        const int lane = tid & 63;                                  // = batch b
        const int j0   = jg * JTILE + w * RJ;

        const float*  wp = W + (size_t)j0 * K3 + rbase * 4;         // uniform
        const float4* fp = FP + (size_t)rbase * BB + lane;

        float acc[RJ];
        #pragma unroll
        for (int jj = 0; jj < RJ; ++jj) acc[jj] = 0.f;

        #pragma unroll 4
        for (int r = 0; r < KCHUNK / 4; ++r) {                      // 48 rows
            const float4 f = fp[(size_t)r * BB];                    // coalesced
            #pragma unroll
            for (int jj = 0; jj < RJ; ++jj) {
                const float4 wv = *(const float4*)(wp + (size_t)jj * K3 + r * 4);
                acc[jj] = fmaf(f.x, wv.x, acc[jj]);
                acc[jj] = fmaf(f.y, wv.y, acc[jj]);
                acc[jj] = fmaf(f.z, wv.z, acc[jj]);
                acc[jj] = fmaf(f.w, wv.w, acc[jj]);
            }
        }

        float* pp = part + ((size_t)kp * HH + j0) * BB + lane;
        #pragma unroll
        for (int jj = 0; jj < RJ; ++jj)
            pp[jj * BB] = acc[jj];                  // coalesced over lanes
    }

    cg::this_grid().sync();

    // ---------------- Phase 2: reduce + bias + tanh (blocks 0..255) ---------
    if (bid < 256) {
        const int j = bid * 4 + (tid >> 6);
        const int b = tid & 63;
        float s = 0.f;
        #pragma unroll
        for (int p = 0; p < KSPLIT; ++p)
            s += part[((size_t)p * HH + j) * BB + b];   // coalesced over lanes
        out[(size_t)b * HH + j] = tanhf(s + bias[j]);
    }
}

// ================= Fallback path (R7 3-kernel, proven 26.3 us) ==============
__global__ __launch_bounds__(512) void feats_kernel(
    const float* __restrict__ hs, const int* __restrict__ subj,
    const int* __restrict__ obj, float4* __restrict__ FP)
{
    const int bid = blockIdx.x;
    const int tid = threadIdx.x;

    if (bid >= 128) {
        const int b = 2 * (bid - 128) + (tid >> 8);
        const int q = tid & 255;
        const float4 v = ((const float4*)(hs + (size_t)b * SS * HH))[q];
        FP[(size_t)q * BB + b] = v;
        return;
    }

    const int b    = bid >> 1;
    const int feat = bid & 1;
    const int* rng = feat ? obj : subj;
    const int s0 = rng[2 * b], s1 = rng[2 * b + 1];
    const int w    = tid >> 6;
    const int lane = tid & 63;

    __shared__ float4 lds[8][256];
    const float4* base = (const float4*)(hs + (size_t)b * SS * HH);

    float4 acc[4];
    #pragma unroll
    for (int q = 0; q < 4; ++q) acc[q] = make_float4(0.f, 0.f, 0.f, 0.f);

    for (int s = s0 + w; s < s1; s += 8) {
        const float4* row = base + (size_t)s * (HH / 4);
        #pragma unroll
        for (int q = 0; q < 4; ++q) {
            float4 v = row[q * 64 + lane];
            acc[q].x += v.x; acc[q].y += v.y; acc[q].z += v.z; acc[q].w += v.w;
        }
    }
    #pragma unroll
    for (int q = 0; q < 4; ++q)
        lds[w][q * 64 + lane] = acc[q];
    __syncthreads();

    if (tid < 256) {
        float4 s = lds[0][tid];
        #pragma unroll
        for (int p = 1; p < 8; ++p) {
            float4 v = lds[p][tid];
            s.x += v.x; s.y += v.y; s.z += v.z; s.w += v.w;
        }
        const float inv = 1.0f / fmaxf((float)(s1 - s0), 1.0f);
        s.x *= inv; s.y *= inv; s.z *= inv; s.w *= inv;
        FP[(size_t)((1 + feat) * 256 + tid) * BB + b] = s;
    }
}

__global__ __launch_bounds__(256) void gemm_kernel(
    const float4* __restrict__ FP, const float* __restrict__ W,
    float* __restrict__ part)
{
    const int bid   = blockIdx.x;
    const int kp    = bid & 15;
    const int jg    = bid >> 4;
    const int rbase = kp * (KCHUNK / 4);
    const int tid   = threadIdx.x;

    const int w    = __builtin_amdgcn_readfirstlane(tid >> 6);
    const int lane = tid & 63;
    const int j0   = jg * JTILE + w * RJ;

    const float*  wp = W + (size_t)j0 * K3 + rbase * 4;
    const float4* fp = FP + (size_t)rbase * BB + lane;

    float acc[RJ];
    #pragma unroll
    for (int jj = 0; jj < RJ; ++jj) acc[jj] = 0.f;

    #pragma unroll 4
    for (int r = 0; r < KCHUNK / 4; ++r) {
        const float4 f = fp[(size_t)r * BB];
        #pragma unroll
        for (int jj = 0; jj < RJ; ++jj) {
            const float4 wv = *(const float4*)(wp + (size_t)jj * K3 + r * 4);
            acc[jj] = fmaf(f.x, wv.x, acc[jj]);
            acc[jj] = fmaf(f.y, wv.y, acc[jj]);
            acc[jj] = fmaf(f.z, wv.z, acc[jj]);
            acc[jj] = fmaf(f.w, wv.w, acc[jj]);
        }
    }

    float* pp = part + ((size_t)kp * HH + j0) * BB + lane;
    #pragma unroll
    for (int jj = 0; jj < RJ; ++jj)
        pp[jj * BB] = acc[jj];
}

__global__ __launch_bounds__(256) void reduce_kernel(
    const float* __restrict__ part, const float* __restrict__ bias,
    float* __restrict__ out)
{
    const int t = threadIdx.x;
    const int j = blockIdx.x * 4 + (t >> 6);
    const int b = t & 63;
    float s = 0.f;
    #pragma unroll
    for (int p = 0; p < KSPLIT; ++p)
        s += part[((size_t)p * HH + j) * BB + b];
    out[(size_t)b * HH + j] = tanhf(s + bias[j]);
}

extern "C" void kernel_launch(void* const* d_in, const int* in_sizes, int n_in,
                              void* d_out, int out_size, void* d_ws, size_t ws_size,
                              hipStream_t stream) {
    const float* hs   = (const float*)d_in[0];
    const int*   subj = (const int*)d_in[1];
    const int*   obj  = (const int*)d_in[2];
    const float* W    = (const float*)d_in[3];
    const float* bias = (const float*)d_in[4];
    float*       out  = (float*)d_out;

    float4* FP   = (float4*)d_ws;                           // 768 KB
    float*  part = (float*)((char*)d_ws + (1 << 20));       // 4 MB at +1 MB

    void* args[] = { (void*)&hs, (void*)&subj, (void*)&obj, (void*)&W,
                     (void*)&bias, (void*)&FP, (void*)&part, (void*)&out };
    hipError_t err = hipLaunchCooperativeKernel(
        (const void*)fused_kernel, dim3(1024), dim3(256), args, 0, stream);

    if (err != hipSuccess) {   // capture-incompatible? fall back to 3 launches
        feats_kernel<<<160, 512, 0, stream>>>(hs, subj, obj, FP);
        gemm_kernel<<<(HH / JTILE) * KSPLIT, 256, 0, stream>>>(FP, W, part);
        reduce_kernel<<<HH / 4, 256, 0, stream>>>(part, bias, out);
    }
}

// Round 9
// 22.175 us; speedup vs baseline: 12.1624x; 12.1624x over previous
//
#include <hip/hip_runtime.h>
#include <math.h>

// B=64, S=512, H=1024
#define BB 64
#define SS 512
#define HH 1024
#define K3 3072
#define KSPLIT 16           // one k-chunk per wave within a block
#define KCHUNK 192          // K3 / KSPLIT -> 48 float4-rows per chunk
#define RJ 4                // j-columns per block (all 16 waves share them)

// Transposed packed feats: FP[r][b] (float4), r = k/4 in [0,768), b in [0,64).
//   r <  256 : first-token  (k < 1024)
//   256..511 : subj-mean    (1024 <= k < 2048)
//   512..767 : obj-mean     (2048 <= k < 3072)
// Lane=b reads feats coalesced (global_load_dwordx4, 1 KB/wave/row).

// ---------------- Kernel 1: build FP (unchanged from R7) --------------------
// grid 160 x 512 threads:
//   bid < 128 : mean job (b = bid>>1, feat = bid&1); 8 waves split rows
//               (serial depth <= 4), LDS reduce, scattered 16B stores to FP.
//   bid >= 128: first-token transpose for 2 batches per block.
__global__ __launch_bounds__(512) void feats_kernel(
    const float* __restrict__ hs,     // (B,S,H)
    const int*   __restrict__ subj,   // (B,2)
    const int*   __restrict__ obj,    // (B,2)
    float4*      __restrict__ FP)     // (768, 64) float4
{
    const int bid = blockIdx.x;
    const int tid = threadIdx.x;

    if (bid >= 128) {                 // first-token transpose (2 b per block)
        const int b = 2 * (bid - 128) + (tid >> 8);
        const int q = tid & 255;
        const float4 v = ((const float4*)(hs + (size_t)b * SS * HH))[q];
        FP[(size_t)q * BB + b] = v;
        return;
    }

    const int b    = bid >> 1;
    const int feat = bid & 1;
    const int* rng = feat ? obj : subj;
    const int s0 = rng[2 * b], s1 = rng[2 * b + 1];

    const int w    = tid >> 6;        // wave 0..7
    const int lane = tid & 63;

    __shared__ float4 lds[8][256];    // 8 wave-partials of H floats (32 KB)

    const float4* base = (const float4*)(hs + (size_t)b * SS * HH);

    float4 acc[4];                    // q -> float4 index q*64+lane
    #pragma unroll
    for (int q = 0; q < 4; ++q) acc[q] = make_float4(0.f, 0.f, 0.f, 0.f);

    for (int s = s0 + w; s < s1; s += 8) {
        const float4* row = base + (size_t)s * (HH / 4);
        #pragma unroll
        for (int q = 0; q < 4; ++q) {
            float4 v = row[q * 64 + lane];
            acc[q].x += v.x; acc[q].y += v.y; acc[q].z += v.z; acc[q].w += v.w;
        }
    }

    #pragma unroll
    for (int q = 0; q < 4; ++q)
        lds[w][q * 64 + lane] = acc[q];
    __syncthreads();

    if (tid < 256) {
        float4 s = lds[0][tid];
        #pragma unroll
        for (int p = 1; p < 8; ++p) {
            float4 v = lds[p][tid];
            s.x += v.x; s.y += v.y; s.z += v.z; s.w += v.w;
        }
        const float inv = 1.0f / fmaxf((float)(s1 - s0), 1.0f);
        s.x *= inv; s.y *= inv; s.z *= inv; s.w *= inv;
        FP[(size_t)((1 + feat) * 256 + tid) * BB + b] = s;   // scattered 16B
    }
}

// ---------------- Kernel 2: GEMM + in-block k-reduce + bias + tanh ----------
// grid 256 = j-groups (4 j each), 1024 threads = 16 waves.
// Wave w owns k-chunk w (R7's proven streaming loop: coalesced FP vloads on
// vmcnt, wave-uniform W s_loads on lgkmcnt, no LDS in the hot loop). Then ONE
// __syncthreads + LDS reduction over the 16 chunk-partials + bias + tanh.
// No part buffer, no third kernel, no cross-block communication.
__global__ __launch_bounds__(1024) void gemm_kernel(
    const float4* __restrict__ FP,    // (768,64) float4
    const float*  __restrict__ W,     // (H,3H) row-major
    const float*  __restrict__ bias,  // (H)
    float*        __restrict__ out)   // (B,H)
{
    __shared__ float red[KSPLIT][RJ][BB];   // 16 KB

    const int jg  = blockIdx.x;             // 0..255
    const int tid = threadIdx.x;

    const int w    = __builtin_amdgcn_readfirstlane(tid >> 6);  // 0..15 uniform
    const int lane = tid & 63;                                  // = batch b
    const int j0   = jg * RJ;
    const int rbase = w * (KCHUNK / 4);     // 48 rows per chunk

    const float*  wp = W + (size_t)j0 * K3 + rbase * 4;         // uniform
    const float4* fp = FP + (size_t)rbase * BB + lane;

    float acc[RJ];
    #pragma unroll
    for (int jj = 0; jj < RJ; ++jj) acc[jj] = 0.f;

    #pragma unroll 4
    for (int r = 0; r < KCHUNK / 4; ++r) {                      // 48 rows
        const float4 f = fp[(size_t)r * BB];                    // coalesced
        #pragma unroll
        for (int jj = 0; jj < RJ; ++jj) {
            const float4 wv = *(const float4*)(wp + (size_t)jj * K3 + r * 4);
            acc[jj] = fmaf(f.x, wv.x, acc[jj]);
            acc[jj] = fmaf(f.y, wv.y, acc[jj]);
            acc[jj] = fmaf(f.z, wv.z, acc[jj]);
            acc[jj] = fmaf(f.w, wv.w, acc[jj]);
        }
    }

    #pragma unroll
    for (int jj = 0; jj < RJ; ++jj)
        red[w][jj][lane] = acc[jj];         // banks: 2-way (free)
    __syncthreads();

    if (tid < RJ * BB) {                    // 256 threads: j = tid>>6, b = tid&63
        const int jj = tid >> 6;
        const int b  = tid & 63;
        float s = 0.f;
        #pragma unroll
        for (int p = 0; p < KSPLIT; ++p)    // fixed order = kp order (bit-stable)
            s += red[p][jj][b];
        const int j = j0 + jj;
        out[(size_t)b * HH + j] = tanhf(s + bias[j]);
    }
}

extern "C" void kernel_launch(void* const* d_in, const int* in_sizes, int n_in,
                              void* d_out, int out_size, void* d_ws, size_t ws_size,
                              hipStream_t stream) {
    const float* hs   = (const float*)d_in[0];  // (B,S,H) fp32
    const int*   subj = (const int*)d_in[1];    // (B,2) int32
    const int*   obj  = (const int*)d_in[2];    // (B,2) int32
    const float* W    = (const float*)d_in[3];  // (H,3H) fp32
    const float* bias = (const float*)d_in[4];  // (H) fp32
    float*       out  = (float*)d_out;          // (B,H) fp32

    float4* FP = (float4*)d_ws;                 // 768 KB scratch

    feats_kernel<<<160, 512, 0, stream>>>(hs, subj, obj, FP);
    gemm_kernel<<<HH / RJ, 1024, 0, stream>>>(FP, W, bias, out);
}

// Round 10
// 19.450 us; speedup vs baseline: 13.8665x; 1.1401x over previous
//
#include <hip/hip_runtime.h>
#include <math.h>

// B=64, S=512, H=1024
#define BB 64
#define SS 512
#define HH 1024
#define K3 3072
#define KSPLIT 16           // one k-chunk per wave within a gemm block
#define KCHUNK 192          // K3 / KSPLIT -> 48 float4-rows per chunk
#define RJ 4                // j-columns per block (all 16 waves share them)

typedef float v2f __attribute__((ext_vector_type(2)));

// Transposed packed feats: FP[r][b] (float4), r = k/4 in [0,768), b in [0,64).
//   r <  256 : first-token  (k < 1024)
//   256..511 : subj-mean    (1024 <= k < 2048)
//   512..767 : obj-mean     (2048 <= k < 3072)

// ---------------- Kernel 1: build FP ----------------------------------------
// grid 144 x 1024 threads:
//   bid < 128 : mean job (b = bid>>1, feat = bid&1); 16 waves split rows
//               stride-16 (serial depth <= 2), LDS reduce, scattered 16B
//               stores into FP.
//   bid >= 128: first-token transpose, 4 batches per block.
__global__ __launch_bounds__(1024) void feats_kernel(
    const float* __restrict__ hs,     // (B,S,H)
    const int*   __restrict__ subj,   // (B,2)
    const int*   __restrict__ obj,    // (B,2)
    float4*      __restrict__ FP)     // (768, 64) float4
{
    const int bid = blockIdx.x;
    const int tid = threadIdx.x;

    if (bid >= 128) {                 // first-token transpose (4 b per block)
        const int b = 4 * (bid - 128) + (tid >> 8);
        const int q = tid & 255;
        const float4 v = ((const float4*)(hs + (size_t)b * SS * HH))[q];
        FP[(size_t)q * BB + b] = v;
        return;
    }

    const int b    = bid >> 1;
    const int feat = bid & 1;
    const int* rng = feat ? obj : subj;
    const int s0 = rng[2 * b], s1 = rng[2 * b + 1];

    const int w    = tid >> 6;        // wave 0..15
    const int lane = tid & 63;

    __shared__ float4 lds[16][256];   // 16 wave-partials of H floats (64 KB)

    const float4* base = (const float4*)(hs + (size_t)b * SS * HH);

    float4 acc[4];                    // q -> float4 index q*64+lane
    #pragma unroll
    for (int q = 0; q < 4; ++q) acc[q] = make_float4(0.f, 0.f, 0.f, 0.f);

    for (int s = s0 + w; s < s1; s += 16) {          // serial depth <= 2
        const float4* row = base + (size_t)s * (HH / 4);
        #pragma unroll
        for (int q = 0; q < 4; ++q) {
            float4 v = row[q * 64 + lane];
            acc[q].x += v.x; acc[q].y += v.y; acc[q].z += v.z; acc[q].w += v.w;
        }
    }

    #pragma unroll
    for (int q = 0; q < 4; ++q)
        lds[w][q * 64 + lane] = acc[q];
    __syncthreads();

    if (tid < 256) {
        float4 s = lds[0][tid];
        #pragma unroll
        for (int p = 1; p < 16; ++p) {
            float4 v = lds[p][tid];
            s.x += v.x; s.y += v.y; s.z += v.z; s.w += v.w;
        }
        const float inv = 1.0f / fmaxf((float)(s1 - s0), 1.0f);
        s.x *= inv; s.y *= inv; s.z *= inv; s.w *= inv;
        FP[(size_t)((1 + feat) * 256 + tid) * BB + b] = s;   // scattered 16B
    }
}

// ---------------- Kernel 2: GEMM + in-block k-reduce + bias + tanh ----------
// grid 256 = j-groups (4 j each), 1024 threads = 16 waves.
// Wave w owns k-chunk w: coalesced FP vloads (vmcnt) + wave-uniform W s_loads
// (lgkmcnt), FMAs packed as v_pk_fma_f32 (k-even/k-odd pairs). One
// __syncthreads + LDS reduce over the 16 chunk-partials + bias + tanh.
__global__ __launch_bounds__(1024) void gemm_kernel(
    const float4* __restrict__ FP,    // (768,64) float4
    const float*  __restrict__ W,     // (H,3H) row-major
    const float*  __restrict__ bias,  // (H)
    float*        __restrict__ out)   // (B,H)
{
    __shared__ float red[KSPLIT][RJ][BB];   // 16 KB

    const int jg  = blockIdx.x;             // 0..255
    const int tid = threadIdx.x;

    const int w    = __builtin_amdgcn_readfirstlane(tid >> 6);  // 0..15 uniform
    const int lane = tid & 63;                                  // = batch b
    const int j0   = jg * RJ;
    const int rbase = w * (KCHUNK / 4);     // 48 rows per chunk

    const float*  wp = W + (size_t)j0 * K3 + rbase * 4;         // uniform
    const float4* fp = FP + (size_t)rbase * BB + lane;

    v2f acc2[RJ];
    #pragma unroll
    for (int jj = 0; jj < RJ; ++jj) acc2[jj] = (v2f)(0.f);

    #pragma unroll 4
    for (int r = 0; r < KCHUNK / 4; ++r) {                      // 48 rows
        const float4 f = fp[(size_t)r * BB];                    // coalesced
        const v2f f01 = { f.x, f.y };
        const v2f f23 = { f.z, f.w };
        #pragma unroll
        for (int jj = 0; jj < RJ; ++jj) {
            const float4 wv = *(const float4*)(wp + (size_t)jj * K3 + r * 4);
            const v2f w01 = { wv.x, wv.y };
            const v2f w23 = { wv.z, wv.w };
            acc2[jj] = __builtin_elementwise_fma(w01, f01, acc2[jj]);   // v_pk_fma_f32
            acc2[jj] = __builtin_elementwise_fma(w23, f23, acc2[jj]);
        }
    }

    #pragma unroll
    for (int jj = 0; jj < RJ; ++jj)
        red[w][jj][lane] = acc2[jj].x + acc2[jj].y;
    __syncthreads();

    if (tid < RJ * BB) {                    // 256 threads: j = tid>>6, b = tid&63
        const int jj = tid >> 6;
        const int b  = tid & 63;
        float s = 0.f;
        #pragma unroll
        for (int p = 0; p < KSPLIT; ++p)    // fixed order (bit-stable)
            s += red[p][jj][b];
        const int j = j0 + jj;
        out[(size_t)b * HH + j] = tanhf(s + bias[j]);
    }
}

extern "C" void kernel_launch(void* const* d_in, const int* in_sizes, int n_in,
                              void* d_out, int out_size, void* d_ws, size_t ws_size,
                              hipStream_t stream) {
    const float* hs   = (const float*)d_in[0];  // (B,S,H) fp32
    const int*   subj = (const int*)d_in[1];    // (B,2) int32
    const int*   obj  = (const int*)d_in[2];    // (B,2) int32
    const float* W    = (const float*)d_in[3];  // (H,3H) fp32
    const float* bias = (const float*)d_in[4];  // (H) fp32
    float*       out  = (float*)d_out;          // (B,H) fp32

    float4* FP = (float4*)d_ws;                 // 768 KB scratch

    feats_kernel<<<144, 1024, 0, stream>>>(hs, subj, obj, FP);
    gemm_kernel<<<HH / RJ, 1024, 0, stream>>>(FP, W, bias, out);
}

// Round 11
// 18.834 us; speedup vs baseline: 14.3194x; 1.0327x over previous
//
#include <hip/hip_runtime.h>
#include <math.h>

// B=64, S=512, H=1024
#define BB 64
#define SS 512
#define HH 1024
#define K3 3072
#define KSPLIT 16           // one k-chunk per wave within a gemm block
#define KCHUNK 192          // K3 / KSPLIT -> 48 bf16x4-rows per chunk
#define RJ 4                // j-columns per block (all 16 waves share them)

typedef float v2f __attribute__((ext_vector_type(2)));
typedef unsigned int u32;

// Transposed packed feats in BF16: FPb[r][b] (uint2 = 4 bf16), r = k/4 in
// [0,768), b in [0,64).
//   r <  256 : first-token  (k < 1024)
//   256..511 : subj-mean    (1024 <= k < 2048)
//   512..767 : obj-mean     (2048 <= k < 3072)
// uint2.x = bf16(k0) | bf16(k1)<<16 ; uint2.y = bf16(k2) | bf16(k3)<<16.
// Lane=b reads FPb coalesced (8B/lane, 512B/wave/row). bf16 halves the
// dominant L2 traffic (196 -> 98 MB); W stays fp32 (read exactly once).

static __device__ __forceinline__ u32 bf16_bits(float v) {
    u32 u = __float_as_uint(v);
    return (u + 0x7fffu + ((u >> 16) & 1u)) >> 16;   // RNE
}
static __device__ __forceinline__ uint2 pack_bf16x4(float4 s) {
    uint2 r;
    r.x = bf16_bits(s.x) | (bf16_bits(s.y) << 16);
    r.y = bf16_bits(s.z) | (bf16_bits(s.w) << 16);
    return r;
}

// ---------------- Kernel 1: build FPb ---------------------------------------
// grid 144 x 1024 threads:
//   bid < 128 : mean job (b = bid>>1, feat = bid&1); 16 waves split rows
//               stride-16 (serial depth <= 2), LDS reduce, scattered 8B
//               stores into FPb.
//   bid >= 128: first-token transpose, 4 batches per block.
__global__ __launch_bounds__(1024) void feats_kernel(
    const float* __restrict__ hs,     // (B,S,H)
    const int*   __restrict__ subj,   // (B,2)
    const int*   __restrict__ obj,    // (B,2)
    uint2*       __restrict__ FPb)    // (768, 64) bf16x4
{
    const int bid = blockIdx.x;
    const int tid = threadIdx.x;

    if (bid >= 128) {                 // first-token transpose (4 b per block)
        const int b = 4 * (bid - 128) + (tid >> 8);
        const int q = tid & 255;
        const float4 v = ((const float4*)(hs + (size_t)b * SS * HH))[q];
        FPb[(size_t)q * BB + b] = pack_bf16x4(v);
        return;
    }

    const int b    = bid >> 1;
    const int feat = bid & 1;
    const int* rng = feat ? obj : subj;
    const int s0 = rng[2 * b], s1 = rng[2 * b + 1];

    const int w    = tid >> 6;        // wave 0..15
    const int lane = tid & 63;

    __shared__ float4 lds[16][256];   // 16 wave-partials of H floats (64 KB)

    const float4* base = (const float4*)(hs + (size_t)b * SS * HH);

    float4 acc[4];                    // q -> float4 index q*64+lane
    #pragma unroll
    for (int q = 0; q < 4; ++q) acc[q] = make_float4(0.f, 0.f, 0.f, 0.f);

    for (int s = s0 + w; s < s1; s += 16) {          // serial depth <= 2
        const float4* row = base + (size_t)s * (HH / 4);
        #pragma unroll
        for (int q = 0; q < 4; ++q) {
            float4 v = row[q * 64 + lane];
            acc[q].x += v.x; acc[q].y += v.y; acc[q].z += v.z; acc[q].w += v.w;
        }
    }

    #pragma unroll
    for (int q = 0; q < 4; ++q)
        lds[w][q * 64 + lane] = acc[q];
    __syncthreads();

    if (tid < 256) {
        float4 s = lds[0][tid];
        #pragma unroll
        for (int p = 1; p < 16; ++p) {
            float4 v = lds[p][tid];
            s.x += v.x; s.y += v.y; s.z += v.z; s.w += v.w;
        }
        const float inv = 1.0f / fmaxf((float)(s1 - s0), 1.0f);
        s.x *= inv; s.y *= inv; s.z *= inv; s.w *= inv;
        FPb[(size_t)((1 + feat) * 256 + tid) * BB + b] = pack_bf16x4(s);
    }
}

// ---------------- Kernel 2: GEMM + in-block k-reduce + bias + tanh ----------
// grid 256 = j-groups (4 j each), 1024 threads = 16 waves.
// Wave w owns k-chunk w: coalesced FPb vloads (8B/lane, vmcnt) unpacked via
// <<16 / &0xffff0000 (exact), wave-uniform W s_loads (fp32, lgkmcnt), FMAs
// packed as v_pk_fma_f32. One __syncthreads + LDS reduce over the 16
// chunk-partials + bias + tanh.
__global__ __launch_bounds__(1024) void gemm_kernel(
    const uint2*  __restrict__ FPb,   // (768,64) bf16x4
    const float*  __restrict__ W,     // (H,3H) row-major
    const float*  __restrict__ bias,  // (H)
    float*        __restrict__ out)   // (B,H)
{
    __shared__ float red[KSPLIT][RJ][BB];   // 16 KB

    const int jg  = blockIdx.x;             // 0..255
    const int tid = threadIdx.x;

    const int w    = __builtin_amdgcn_readfirstlane(tid >> 6);  // 0..15 uniform
    const int lane = tid & 63;                                  // = batch b
    const int j0   = jg * RJ;
    const int rbase = w * (KCHUNK / 4);     // 48 rows per chunk

    const float* wp = W + (size_t)j0 * K3 + rbase * 4;          // uniform
    const uint2* fp = FPb + (size_t)rbase * BB + lane;

    v2f acc2[RJ];
    #pragma unroll
    for (int jj = 0; jj < RJ; ++jj) acc2[jj] = (v2f)(0.f);

    #pragma unroll 4
    for (int r = 0; r < KCHUNK / 4; ++r) {                      // 48 rows
        const uint2 u = fp[(size_t)r * BB];                     // coalesced 8B
        const v2f f01 = { __uint_as_float(u.x << 16),
                          __uint_as_float(u.x & 0xffff0000u) };
        const v2f f23 = { __uint_as_float(u.y << 16),
                          __uint_as_float(u.y & 0xffff0000u) };
        #pragma unroll
        for (int jj = 0; jj < RJ; ++jj) {
            const float4 wv = *(const float4*)(wp + (size_t)jj * K3 + r * 4);
            const v2f w01 = { wv.x, wv.y };
            const v2f w23 = { wv.z, wv.w };
            acc2[jj] = __builtin_elementwise_fma(w01, f01, acc2[jj]);   // v_pk_fma_f32
            acc2[jj] = __builtin_elementwise_fma(w23, f23, acc2[jj]);
        }
    }

    #pragma unroll
    for (int jj = 0; jj < RJ; ++jj)
        red[w][jj][lane] = acc2[jj].x + acc2[jj].y;
    __syncthreads();

    if (tid < RJ * BB) {                    // 256 threads: j = tid>>6, b = tid&63
        const int jj = tid >> 6;
        const int b  = tid & 63;
        float s = 0.f;
        #pragma unroll
        for (int p = 0; p < KSPLIT; ++p)    // fixed order (bit-stable)
            s += red[p][jj][b];
        const int j = j0 + jj;
        out[(size_t)b * HH + j] = tanhf(s + bias[j]);
    }
}

extern "C" void kernel_launch(void* const* d_in, const int* in_sizes, int n_in,
                              void* d_out, int out_size, void* d_ws, size_t ws_size,
                              hipStream_t stream) {
    const float* hs   = (const float*)d_in[0];  // (B,S,H) fp32
    const int*   subj = (const int*)d_in[1];    // (B,2) int32
    const int*   obj  = (const int*)d_in[2];    // (B,2) int32
    const float* W    = (const float*)d_in[3];  // (H,3H) fp32
    const float* bias = (const float*)d_in[4];  // (H) fp32
    float*       out  = (float*)d_out;          // (B,H) fp32

    uint2* FPb = (uint2*)d_ws;                  // 384 KB scratch

    feats_kernel<<<144, 1024, 0, stream>>>(hs, subj, obj, FPb);
    gemm_kernel<<<HH / RJ, 1024, 0, stream>>>(FPb, W, bias, out);
}